// Round 1
// baseline (326.978 us; speedup 1.0000x reference)
//
#include <hip/hip_runtime.h>

// Problem constants (from reference): x [8,128,96,96] fp32, W [384,128] fp32.
#define NB     8      // batch
#define CIN    128    // input channels
#define NOUT   384    // 3*CIN
#define HEADS  4
#define DHEAD  32     // CIN/HEADS
#define HDIM   96
#define WDIM   96
#define HW     9216   // 96*96
#define TP     64     // positions per GEMM block

// ---------------------------------------------------------------------------
// Stage 1: QKV projection (1x1 conv == GEMM over channels), fp32 vector ALU.
// qkv layout: [which(3)][b(8)][g(4)][p(9216)][d(32)]  (d innermost, float4-able)
// ---------------------------------------------------------------------------
__global__ __launch_bounds__(256) void qkv_kernel(
    const float* __restrict__ x, const float* __restrict__ W,
    float* __restrict__ qkv) {
  __shared__ float xs[CIN][TP];   // 32 KB; reads xs[c][p] lanes=p -> 2-way (free)
  const int b  = blockIdx.y;
  const int p0 = blockIdx.x * TP;
  const int tid = threadIdx.x;

  const float* xb = x + (size_t)b * CIN * HW + p0;
#pragma unroll
  for (int i = 0; i < CIN * TP / 256; ++i) {
    int idx = i * 256 + tid;
    int c = idx >> 6, p = idx & (TP - 1);
    xs[c][p] = xb[(size_t)c * HW + p];   // coalesced 256B per wave
  }
  __syncthreads();

  const int p  = tid & 63;
  // force wave-uniform so W loads become s_load (scalar cache), not vmem
  const int og = __builtin_amdgcn_readfirstlane(tid >> 6);
  const int gp = p0 + p;

  // 96 o-quads total; this thread owns quads qq = og + 4*(4t+u), t in 0..5, u in 0..3
  for (int t = 0; t < 6; ++t) {
    float acc[16];
#pragma unroll
    for (int i = 0; i < 16; ++i) acc[i] = 0.0f;
    int ob[4];
#pragma unroll
    for (int u = 0; u < 4; ++u) ob[u] = 4 * (og + 4 * (4 * t + u));

#pragma unroll 4
    for (int c = 0; c < CIN; ++c) {
      float xv = xs[c][p];               // 1 ds_read feeds 16 FMAs
#pragma unroll
      for (int u = 0; u < 4; ++u) {
#pragma unroll
        for (int j = 0; j < 4; ++j)
          acc[u * 4 + j] = fmaf(W[(size_t)(ob[u] + j) * CIN + c], xv, acc[u * 4 + j]);
      }
    }

#pragma unroll
    for (int u = 0; u < 4; ++u) {
      const int o0 = ob[u];
      const int which = o0 >> 7;          // 0=q, 1=k, 2=v
      const int rem = o0 & 127;
      const int g = rem >> 5, d = rem & 31;
      float* dst = qkv + ((size_t)(which * NB + b) * HEADS + g) * ((size_t)HW * DHEAD)
                   + (size_t)gp * DHEAD + d;
      *(float4*)dst = make_float4(acc[u * 4 + 0], acc[u * 4 + 1],
                                  acc[u * 4 + 2], acc[u * 4 + 3]);
    }
  }
}

// ---------------------------------------------------------------------------
// Stage 2: 3x3 neighborhood attention. One thread per (b,g,h,w).
// Zero-padded k => OOB neighbor logit == 0 (participates in softmax denom);
// zero-padded v => OOB contributes nothing to numerator.
// ---------------------------------------------------------------------------
__global__ __launch_bounds__(256) void attn_kernel(
    const float* __restrict__ qkv, float* __restrict__ out) {
  const int bg = blockIdx.z;                       // b*4 + g
  const int h  = blockIdx.y * 8 + threadIdx.y;
  const int w  = blockIdx.x * 32 + threadIdx.x;
  const int b  = bg >> 2, g = bg & 3;

  const size_t plane = (size_t)HW * DHEAD;
  const float* Qb = qkv + (size_t)bg * plane;
  const float* Kb = qkv + (size_t)(32 + bg) * plane;
  const float* Vb = qkv + (size_t)(64 + bg) * plane;
  const int p = h * WDIM + w;

  float4 q[8];
  const float4* qp = (const float4*)(Qb + (size_t)p * DHEAD);
#pragma unroll
  for (int i = 0; i < 8; ++i) q[i] = qp[i];

  float att[9];
#pragma unroll
  for (int n = 0; n < 9; ++n) {
    const int dy = n / 3 - 1, dx = n % 3 - 1;
    const int hh = h + dy, ww = w + dx;
    float dot = 0.0f;
    if (hh >= 0 && hh < HDIM && ww >= 0 && ww < WDIM) {
      const float4* kp = (const float4*)(Kb + (size_t)(hh * WDIM + ww) * DHEAD);
#pragma unroll
      for (int i = 0; i < 8; ++i) {
        float4 kv = kp[i];
        dot = fmaf(q[i].x, kv.x, dot);
        dot = fmaf(q[i].y, kv.y, dot);
        dot = fmaf(q[i].z, kv.z, dot);
        dot = fmaf(q[i].w, kv.w, dot);
      }
      dot *= 0.17677669529663687f;   // 1/sqrt(32)
    }
    att[n] = dot;                    // OOB: exact 0 logit, matches zero-pad
  }

  float m = att[0];
#pragma unroll
  for (int n = 1; n < 9; ++n) m = fmaxf(m, att[n]);
  float s = 0.0f;
#pragma unroll
  for (int n = 0; n < 9; ++n) { att[n] = __expf(att[n] - m); s += att[n]; }
  const float inv = 1.0f / s;

  float4 acc[8];
#pragma unroll
  for (int i = 0; i < 8; ++i) acc[i] = make_float4(0.f, 0.f, 0.f, 0.f);
#pragma unroll
  for (int n = 0; n < 9; ++n) {
    const int dy = n / 3 - 1, dx = n % 3 - 1;
    const int hh = h + dy, ww = w + dx;
    if (hh >= 0 && hh < HDIM && ww >= 0 && ww < WDIM) {
      const float wn = att[n] * inv;
      const float4* vp = (const float4*)(Vb + (size_t)(hh * WDIM + ww) * DHEAD);
#pragma unroll
      for (int i = 0; i < 8; ++i) {
        float4 vv = vp[i];
        acc[i].x = fmaf(wn, vv.x, acc[i].x);
        acc[i].y = fmaf(wn, vv.y, acc[i].y);
        acc[i].z = fmaf(wn, vv.z, acc[i].z);
        acc[i].w = fmaf(wn, vv.w, acc[i].w);
      }
    }
  }

  // out layout [b][C=128][96][96]; channel = g*32 + d; lanes along w -> coalesced
  float* ob = out + ((size_t)b * CIN + (size_t)g * DHEAD) * HW + p;
#pragma unroll
  for (int i = 0; i < 8; ++i) {
    ob[(size_t)(4 * i + 0) * HW] = acc[i].x;
    ob[(size_t)(4 * i + 1) * HW] = acc[i].y;
    ob[(size_t)(4 * i + 2) * HW] = acc[i].z;
    ob[(size_t)(4 * i + 3) * HW] = acc[i].w;
  }
}

extern "C" void kernel_launch(void* const* d_in, const int* in_sizes, int n_in,
                              void* d_out, int out_size, void* d_ws, size_t ws_size,
                              hipStream_t stream) {
  (void)in_sizes; (void)n_in; (void)out_size; (void)ws_size;
  const float* x = (const float*)d_in[0];   // [8,128,96,96]
  const float* W = (const float*)d_in[1];   // [384,128]
  float* out = (float*)d_out;               // [8,128,96,96]
  float* qkv = (float*)d_ws;                // needs 3*8*4*9216*32*4 = 113 MB

  dim3 g1(HW / TP, NB);                     // (144, 8)
  qkv_kernel<<<g1, 256, 0, stream>>>(x, W, qkv);

  dim3 g2(WDIM / 32, HDIM / 8, NB * HEADS); // (3, 12, 32)
  attn_kernel<<<g2, dim3(32, 8, 1), 0, stream>>>(qkv, out);
}

// Round 2
// 127.716 us; speedup vs baseline: 2.5602x; 2.5602x over previous
//
#include <hip/hip_runtime.h>

// Problem constants: x [8,128,96,96] fp32, W [384,128] fp32, out [8,128,96,96] fp32.
#define NB     8
#define CIN    128
#define HEADS  4
#define DHEAD  32
#define HDIM   96
#define WDIM   96
#define HW     9216
#define TP     64    // positions per stage-1 block

typedef __bf16 bf16x8 __attribute__((ext_vector_type(8)));
typedef float  f32x4  __attribute__((ext_vector_type(4)));

__device__ __forceinline__ unsigned f2bf(float f) {
  unsigned u = __float_as_uint(f);
  return (u + 0x7fffu + ((u >> 16) & 1u)) >> 16;   // RNE
}
__device__ __forceinline__ unsigned pack2(float a, float b) {
  return f2bf(a) | (f2bf(b) << 16);
}
__device__ __forceinline__ float bflo(unsigned u) { return __uint_as_float(u << 16); }
__device__ __forceinline__ float bfhi(unsigned u) { return __uint_as_float(u & 0xffff0000u); }

// ---------------------------------------------------------------------------
// Prep: pack W [384][128] fp32 into A-fragment-ordered bf16 global buffer.
// Frag (ot,kb): lane l holds A[o=ot*16+(l&15)][c=kb*32+(l>>4)*8+j], j=0..7 (16B).
// ---------------------------------------------------------------------------
__global__ __launch_bounds__(256) void wpack_kernel(const float* __restrict__ W,
                                                    uint4* __restrict__ Wf) {
  const int u = blockIdx.x * 256 + threadIdx.x;   // 0..6143 = 24 ot * 4 kb * 64 lanes
  const int lane = u & 63, kb = (u >> 6) & 3, ot = u >> 8;
  const int o = ot * 16 + (lane & 15);
  const int c0 = kb * 32 + (lane >> 4) * 8;
  const float4* w = (const float4*)(W + (size_t)o * CIN + c0);
  float4 w0 = w[0], w1 = w[1];
  uint4 r;
  r.x = pack2(w0.x, w0.y); r.y = pack2(w0.z, w0.w);
  r.z = pack2(w1.x, w1.y); r.w = pack2(w1.z, w1.w);
  Wf[u] = r;
}

// ---------------------------------------------------------------------------
// Stage 1: QKV projection via bf16 MFMA. C[o][p] = sum_c W[o][c] * x[c][p].
// qkv layout: [which(3)][b][g(4)][p(9216)][d(32)] bf16.
// ---------------------------------------------------------------------------
__global__ __launch_bounds__(256) void qkv_kernel(const float* __restrict__ x,
                                                  const uint4* __restrict__ Wf,
                                                  unsigned short* __restrict__ qkvb) {
  // B-frags for 4 p-tiles x 4 k-blocks, 64 lanes x 16B each = 16 KB
  __shared__ uint4 xs[16 * 64];
  const int b  = blockIdx.y;
  const int p0 = blockIdx.x * TP;
  const int t  = threadIdx.x;

  // ---- load x tile [128 c][64 p], convert bf16, store in B-frag order ----
  {
    const int p = t & 63, cg_hi = t >> 6;
    const int pt = p >> 4, n = p & 15;
    const float* xb = x + (size_t)b * CIN * HW + p0 + p;
#pragma unroll
    for (int i = 0; i < 4; ++i) {
      const int cg = i * 4 + cg_hi;        // 0..15 (octet of channels)
      const int c0 = cg * 8;
      const int kb = cg >> 2, q = cg & 3;
      float f[8];
#pragma unroll
      for (int j = 0; j < 8; ++j) f[j] = xb[(size_t)(c0 + j) * HW];  // coalesced
      uint4 r;
      r.x = pack2(f[0], f[1]); r.y = pack2(f[2], f[3]);
      r.z = pack2(f[4], f[5]); r.w = pack2(f[6], f[7]);
      xs[(pt * 4 + kb) * 64 + q * 16 + n] = r;
    }
  }
  __syncthreads();

  // ---- compute: wave wv covers o-tiles 6*wv .. 6*wv+5, all 4 p-tiles ----
  const int wv = t >> 6, lane = t & 63;
  const int colp = lane & 15, quad = lane >> 4;
#pragma unroll 1
  for (int it = 0; it < 6; ++it) {
    const int ot = wv * 6 + it;
    bf16x8 afrag[4];
#pragma unroll
    for (int kb = 0; kb < 4; ++kb) {
      uint4 tmp = Wf[(ot * 4 + kb) * 64 + lane];   // L2-hot, coalesced
      afrag[kb] = *(bf16x8*)&tmp;
    }
    const int o0 = ot * 16 + quad * 4;             // 4 consecutive o for regs 0..3
    const int which = o0 >> 7, g = (o0 & 127) >> 5, d0 = o0 & 31;
    unsigned short* dst = qkvb
        + (((size_t)(which * NB + b) * HEADS + g) * HW) * DHEAD + d0;
#pragma unroll
    for (int pt = 0; pt < 4; ++pt) {
      f32x4 acc = {0.f, 0.f, 0.f, 0.f};
#pragma unroll
      for (int kb = 0; kb < 4; ++kb) {
        bf16x8 bfrag = *(bf16x8*)&xs[(pt * 4 + kb) * 64 + lane];
        acc = __builtin_amdgcn_mfma_f32_16x16x32_bf16(afrag[kb], bfrag, acc, 0, 0, 0);
      }
      const int pp = p0 + pt * 16 + colp;
      uint2 st;                                     // d0..d0+3 as bf16x4
      st.x = pack2(acc[0], acc[1]);
      st.y = pack2(acc[2], acc[3]);
      *(uint2*)(dst + (size_t)pp * DHEAD) = st;
    }
  }
}

// ---------------------------------------------------------------------------
// Stage 2: 3x3 neighborhood attention, bf16 qkv in, fp32 out.
// One thread per (b,g,h,w). OOB neighbor => logit exactly 0 (zero-pad semantics).
// ---------------------------------------------------------------------------
__global__ __launch_bounds__(256) void attn_kernel(const unsigned short* __restrict__ qkvb,
                                                   float* __restrict__ out) {
  const int bg = blockIdx.z;                        // b*4+g
  const int h  = blockIdx.y * 8 + threadIdx.y;
  const int w  = blockIdx.x * 32 + threadIdx.x;
  const int b  = bg >> 2, g = bg & 3;

  const size_t plane = (size_t)HW * DHEAD;          // in ushorts
  const uint4* Qb = (const uint4*)(qkvb + (size_t)bg * plane);
  const uint4* Kb = (const uint4*)(qkvb + (size_t)(32 + bg) * plane);
  const uint4* Vb = (const uint4*)(qkvb + (size_t)(64 + bg) * plane);
  const int p = h * WDIM + w;

  float q[32];
#pragma unroll
  for (int i = 0; i < 4; ++i) {
    uint4 u = Qb[p * 4 + i];
    q[i * 8 + 0] = bflo(u.x); q[i * 8 + 1] = bfhi(u.x);
    q[i * 8 + 2] = bflo(u.y); q[i * 8 + 3] = bfhi(u.y);
    q[i * 8 + 4] = bflo(u.z); q[i * 8 + 5] = bfhi(u.z);
    q[i * 8 + 6] = bflo(u.w); q[i * 8 + 7] = bfhi(u.w);
  }

  float att[9];
#pragma unroll
  for (int nn = 0; nn < 9; ++nn) {
    const int dy = nn / 3 - 1, dx = nn % 3 - 1;
    const int hh = h + dy, ww = w + dx;
    float dot = 0.0f;
    if (hh >= 0 && hh < HDIM && ww >= 0 && ww < WDIM) {
      const int pn = hh * WDIM + ww;
#pragma unroll
      for (int i = 0; i < 4; ++i) {
        uint4 u = Kb[pn * 4 + i];
        dot = fmaf(q[i * 8 + 0], bflo(u.x), dot);
        dot = fmaf(q[i * 8 + 1], bfhi(u.x), dot);
        dot = fmaf(q[i * 8 + 2], bflo(u.y), dot);
        dot = fmaf(q[i * 8 + 3], bfhi(u.y), dot);
        dot = fmaf(q[i * 8 + 4], bflo(u.z), dot);
        dot = fmaf(q[i * 8 + 5], bfhi(u.z), dot);
        dot = fmaf(q[i * 8 + 6], bflo(u.w), dot);
        dot = fmaf(q[i * 8 + 7], bfhi(u.w), dot);
      }
      dot *= 0.17677669529663687f;   // 1/sqrt(32)
    }
    att[nn] = dot;
  }

  float m = att[0];
#pragma unroll
  for (int nn = 1; nn < 9; ++nn) m = fmaxf(m, att[nn]);
  float s = 0.0f;
#pragma unroll
  for (int nn = 0; nn < 9; ++nn) { att[nn] = __expf(att[nn] - m); s += att[nn]; }
  const float inv = 1.0f / s;

  float acc[32];
#pragma unroll
  for (int i = 0; i < 32; ++i) acc[i] = 0.0f;
#pragma unroll
  for (int nn = 0; nn < 9; ++nn) {
    const int dy = nn / 3 - 1, dx = nn % 3 - 1;
    const int hh = h + dy, ww = w + dx;
    if (hh >= 0 && hh < HDIM && ww >= 0 && ww < WDIM) {
      const float wn = att[nn] * inv;
      const int pn = hh * WDIM + ww;
#pragma unroll
      for (int i = 0; i < 4; ++i) {
        uint4 u = Vb[pn * 4 + i];
        acc[i * 8 + 0] = fmaf(wn, bflo(u.x), acc[i * 8 + 0]);
        acc[i * 8 + 1] = fmaf(wn, bfhi(u.x), acc[i * 8 + 1]);
        acc[i * 8 + 2] = fmaf(wn, bflo(u.y), acc[i * 8 + 2]);
        acc[i * 8 + 3] = fmaf(wn, bfhi(u.y), acc[i * 8 + 3]);
        acc[i * 8 + 4] = fmaf(wn, bflo(u.z), acc[i * 8 + 4]);
        acc[i * 8 + 5] = fmaf(wn, bfhi(u.z), acc[i * 8 + 5]);
        acc[i * 8 + 6] = fmaf(wn, bflo(u.w), acc[i * 8 + 6]);
        acc[i * 8 + 7] = fmaf(wn, bfhi(u.w), acc[i * 8 + 7]);
      }
    }
  }

  // out [b][C=128][96][96]; channel = g*32 + d; lanes along w -> coalesced
  float* ob = out + ((size_t)b * CIN + (size_t)g * DHEAD) * HW + p;
#pragma unroll
  for (int i = 0; i < 32; ++i) ob[(size_t)i * HW] = acc[i];
}

extern "C" void kernel_launch(void* const* d_in, const int* in_sizes, int n_in,
                              void* d_out, int out_size, void* d_ws, size_t ws_size,
                              hipStream_t stream) {
  (void)in_sizes; (void)n_in; (void)out_size; (void)ws_size;
  const float* x = (const float*)d_in[0];   // [8,128,96,96]
  const float* W = (const float*)d_in[1];   // [384,128]
  float* out = (float*)d_out;

  const size_t qkv_ushorts = (size_t)3 * NB * HEADS * HW * DHEAD;  // 28.3M -> 56.6 MB
  unsigned short* qkvb = (unsigned short*)d_ws;
  uint4* Wf = (uint4*)((char*)d_ws + qkv_ushorts * 2);             // 98 KB more

  wpack_kernel<<<24, 256, 0, stream>>>(W, Wf);
  qkv_kernel<<<dim3(HW / TP, NB), 256, 0, stream>>>(x, Wf, qkvb);
  attn_kernel<<<dim3(WDIM / 32, HDIM / 8, NB * HEADS), dim3(32, 8, 1), 0, stream>>>(qkvb, out);
}